// Round 9
// baseline (63.831 us; speedup 1.0000x reference)
//
#include <hip/hip_runtime.h>

// DepthLossForImgBEV: weighted BCE over (B,N,D,H,W) depth logits vs one-hot
// bucketized GT depth, reduced to a scalar mean * 3.0.
//
// B=2 N=6 D=112 H=64 W=176.  depth: (B,N*D,H,W) f32 (60.6 MB); depth_gt:
// (B,N,H,W) f32 (0.54 MB, cache-resident).
//
// History: R4 two-kernel (DPC=16, 924x256, xv[16] batch) = 20.8 us best.
// Geometry variants all land 21-22 -> a FIXED cost (k2 dispatch + inter-node
// drain ~5-8 us) dominates, not k1 shape. Coop launch failed twice (dead).
// R8's scattered x_idx gathers regressed (reverted).
//
// R9: single dispatch. k1 body identical to R4; after the partial store,
// device-scope ticket atomicAdd; the block taking ticket NBLK-1 (all partials
// fenced + visible) reduces part[0..923] in fixed order -> deterministic
// scalar. Counter zeroed by a 4B memset node each replay (R0's 42us is now
// attributed to its 2048 same-line atomics, not the memset).

namespace {

constexpr int B_ = 2, N_ = 6, D_ = 112, H_ = 64, W_ = 176;
constexpr int HW_   = H_ * W_;          // 11264
constexpr int NHWQ_ = HW_ / 4;          // 2816 float4 quads per image plane
constexpr int DPC_  = 16, NCH_ = 7;     // 7 d-chunks x 16 slices = 112
constexpr int NBN_  = B_ * N_;          // 12
constexpr long long TOT_ = (long long)NBN_ * D_ * HW_;   // 15,138,816
constexpr int NTHR_ = NBN_ * NCH_ * NHWQ_;               // 236,544
constexpr int NBLK_ = NTHR_ / 256;                       // 924 blocks
constexpr int NQUAD_ = NBLK_ / 4;                        // 231 float4s of partials
constexpr float SCALE_ = (float)(3.0 / (double)TOT_);    // 3.0 / numel

// bce = min(softplus(+-x), 100) * w;  softplus(x) = relu(x) + log1p(exp(-|x|))
__device__ __forceinline__ float term(float x, float w, bool hit) {
    float c = __logf(1.0f + __expf(-fabsf(x)));          // shared log term
    float r = hit ? fmaxf(-x, 0.0f) : fmaxf(x, 0.0f);
    return w * fminf(c + r, 100.0f);
}

__device__ __forceinline__ int bucket(float g) {
    int i = (int)floorf((g - 2.0f) * 2.0f);   // (g - DBOUND0) / DBOUND2
    return i < 0 ? 0 : (i > D_ ? D_ : i);     // clip [0,D]; D never matches d
}

__global__ __launch_bounds__(256) void depth_loss_fused(
        const float* __restrict__ gt, const float* __restrict__ dp,
        float* __restrict__ part, int* __restrict__ ticket,
        float* __restrict__ out) {
    const int t    = blockIdx.x * 256 + threadIdx.x;
    const int hwq  = t % NHWQ_;           // quad within image plane
    const int rest = t / NHWQ_;
    const int ch   = rest % NCH_;         // which 16-slice d-chunk
    const int bn   = rest / NCH_;         // (b*N + n)
    const int hw   = hwq * 4;
    const int d0   = ch * DPC_;

    // batch-issue all 16 slice loads (static indices -> 64 live VGPRs)
    const float* p = dp + ((bn * D_ + d0) * HW_ + hw);
    float4 xv[DPC_];
    #pragma unroll
    for (int i = 0; i < DPC_; ++i)
        xv[i] = *reinterpret_cast<const float4*>(p + (size_t)i * HW_);

    // gt quad + bucket math while slice loads are in flight
    const float4 g = *reinterpret_cast<const float4*>(gt + bn * HW_ + hw);
    const float w0 = (g.x != 0.0f) ? 1.0f : 0.0f;
    const float w1 = (g.y != 0.0f) ? 1.0f : 0.0f;
    const float w2 = (g.z != 0.0f) ? 1.0f : 0.0f;
    const float w3 = (g.w != 0.0f) ? 1.0f : 0.0f;
    const int  i0 = bucket(g.x), i1 = bucket(g.y), i2 = bucket(g.z), i3 = bucket(g.w);

    float s = 0.0f;
    #pragma unroll
    for (int i = 0; i < DPC_; ++i) {
        const int d = d0 + i;
        s += term(xv[i].x, w0, d == i0);
        s += term(xv[i].y, w1, d == i1);
        s += term(xv[i].z, w2, d == i2);
        s += term(xv[i].w, w3, d == i3);
    }

    // block reduce -> one partial per block
    #pragma unroll
    for (int off = 32; off > 0; off >>= 1) s += __shfl_down(s, off, 64);
    __shared__ float ls[4];
    __shared__ int last;
    if ((threadIdx.x & 63) == 0) ls[threadIdx.x >> 6] = s;
    __syncthreads();
    if (threadIdx.x == 0) {
        part[blockIdx.x] = (ls[0] + ls[1]) + (ls[2] + ls[3]);
        __threadfence();   // publish partial before taking a ticket (device scope)
        int old = __hip_atomic_fetch_add(ticket, 1, __ATOMIC_ACQ_REL,
                                         __HIP_MEMORY_SCOPE_AGENT);
        last = (old == NBLK_ - 1);   // ticket NBLK-1: all 924 partials published
    }
    __syncthreads();

    if (last) {
        __threadfence();   // acquire side for all lanes' part[] reads
        float r = 0.0f;
        if (threadIdx.x < NQUAD_) {
            float4 q = reinterpret_cast<const float4*>(part)[threadIdx.x];
            r = (q.x + q.y) + (q.z + q.w);
        }
        #pragma unroll
        for (int off = 32; off > 0; off >>= 1) r += __shfl_down(r, off, 64);
        if ((threadIdx.x & 63) == 0) ls[threadIdx.x >> 6] = r;
        __syncthreads();
        if (threadIdx.x == 0)
            out[0] = ((ls[0] + ls[1]) + (ls[2] + ls[3])) * SCALE_;
    }
}

}  // namespace

extern "C" void kernel_launch(void* const* d_in, const int* in_sizes, int n_in,
                              void* d_out, int out_size, void* d_ws, size_t ws_size,
                              hipStream_t stream) {
    const float* gt = (const float*)d_in[0];   // depth_gt (B,N,H,W)
    const float* dp = (const float*)d_in[1];   // depth (B,N*D,H,W)
    float* part = (float*)d_ws;                // 924 floats of scratch
    int* ticket = (int*)((char*)d_ws + 4096);  // 4B counter, separate line
    float* out  = (float*)d_out;
    hipMemsetAsync(ticket, 0, sizeof(int), stream);   // zero ticket each replay
    depth_loss_fused<<<NBLK_, 256, 0, stream>>>(gt, dp, part, ticket, out);
}

// Round 10
// 20.556 us; speedup vs baseline: 3.1052x; 3.1052x over previous
//
#include <hip/hip_runtime.h>

// DepthLossForImgBEV: weighted BCE over (B,N,D,H,W) depth logits vs one-hot
// bucketized GT depth, reduced to a scalar mean * 3.0.
//
// B=2 N=6 D=112 H=64 W=176.  depth: (B,N*D,H,W) f32 (60.6 MB, ~half
// L3-resident per FETCH_SIZE=31.5 MB); depth_gt: (B,N,H,W) f32 (cache-hot).
//
// History: R4 two-kernel (DPC=16, 924x256, xv[16]) = 20.8 us best. All fused
// variants (R3 coop / R9 ticket) compiled to VGPR=16/32 -- the compiler's
// occupancy heuristic serialized the 16 batched loads -> 0.3-0.5 TB/s
// latency-bound. R4's k1 VGPR was never observed; its geometry-insensitivity
// (R2/R4/R7 all 21-22us) suggests it TOO was serialized.
//
// R10: R4 body + an empty `asm volatile` consuming all 64 components after
// the load loop. The compiler must hold all 16 float4s live at that point:
// it cannot sink loads into the compute loop or allocate <~70 VGPRs. This
// guarantees 16 outstanding loads/thread (true MLP), which TLP then overlaps.

namespace {

constexpr int B_ = 2, N_ = 6, D_ = 112, H_ = 64, W_ = 176;
constexpr int HW_   = H_ * W_;          // 11264
constexpr int NHWQ_ = HW_ / 4;          // 2816 float4 quads per image plane
constexpr int DPC_  = 16, NCH_ = 7;     // 7 d-chunks x 16 slices = 112
constexpr int NBN_  = B_ * N_;          // 12
constexpr long long TOT_ = (long long)NBN_ * D_ * HW_;   // 15,138,816
constexpr int NTHR_ = NBN_ * NCH_ * NHWQ_;               // 236,544
constexpr int NBLK_ = NTHR_ / 256;                       // 924 blocks
constexpr float SCALE_ = (float)(3.0 / (double)TOT_);    // 3.0 / numel

// bce = min(softplus(+-x), 100) * w;  softplus(x) = relu(x) + log1p(exp(-|x|))
__device__ __forceinline__ float term(float x, float w, bool hit) {
    float c = __logf(1.0f + __expf(-fabsf(x)));          // shared log term
    float r = hit ? fmaxf(-x, 0.0f) : fmaxf(x, 0.0f);
    return w * fminf(c + r, 100.0f);
}

__device__ __forceinline__ int bucket(float g) {
    int i = (int)floorf((g - 2.0f) * 2.0f);   // (g - DBOUND0) / DBOUND2
    return i < 0 ? 0 : (i > D_ ? D_ : i);     // clip [0,D]; D never matches d
}

__global__ __launch_bounds__(256) void depth_loss_part(
        const float* __restrict__ gt, const float* __restrict__ dp,
        float* __restrict__ part) {
    const int t    = blockIdx.x * 256 + threadIdx.x;
    const int hwq  = t % NHWQ_;           // quad within image plane
    const int rest = t / NHWQ_;
    const int ch   = rest % NCH_;         // which 16-slice d-chunk
    const int bn   = rest / NCH_;         // (b*N + n)
    const int hw   = hwq * 4;
    const int d0   = ch * DPC_;

    // issue gt + all 16 slice loads back-to-back
    const float4 g = *reinterpret_cast<const float4*>(gt + bn * HW_ + hw);
    const float* p = dp + ((bn * D_ + d0) * HW_ + hw);
    float4 xv[DPC_];
    #pragma unroll
    for (int i = 0; i < DPC_; ++i)
        xv[i] = *reinterpret_cast<const float4*>(p + (size_t)i * HW_);

    // KEEP-ALIVE FENCE: forces all 16 float4s (64 VGPRs) live here -> the
    // compiler cannot serialize the loads into the compute loop (R3/R9 bug).
    #pragma unroll
    for (int i = 0; i < DPC_; ++i)
        asm volatile("" :: "v"(xv[i].x), "v"(xv[i].y), "v"(xv[i].z), "v"(xv[i].w));

    const float w0 = (g.x != 0.0f) ? 1.0f : 0.0f;
    const float w1 = (g.y != 0.0f) ? 1.0f : 0.0f;
    const float w2 = (g.z != 0.0f) ? 1.0f : 0.0f;
    const float w3 = (g.w != 0.0f) ? 1.0f : 0.0f;
    const int  i0 = bucket(g.x), i1 = bucket(g.y), i2 = bucket(g.z), i3 = bucket(g.w);

    float s = 0.0f;
    #pragma unroll
    for (int i = 0; i < DPC_; ++i) {
        const int d = d0 + i;
        s += term(xv[i].x, w0, d == i0);
        s += term(xv[i].y, w1, d == i1);
        s += term(xv[i].z, w2, d == i2);
        s += term(xv[i].w, w3, d == i3);
    }

    // block reduce -> one partial per block (overwrite, no init needed)
    #pragma unroll
    for (int off = 32; off > 0; off >>= 1) s += __shfl_down(s, off, 64);
    __shared__ float ls[4];
    if ((threadIdx.x & 63) == 0) ls[threadIdx.x >> 6] = s;
    __syncthreads();
    if (threadIdx.x == 0)
        part[blockIdx.x] = (ls[0] + ls[1]) + (ls[2] + ls[3]);
}

__global__ __launch_bounds__(256) void depth_loss_final(
        const float* __restrict__ part, float* __restrict__ out) {
    float s = part[threadIdx.x] + part[threadIdx.x + 256] + part[threadIdx.x + 512];
    if (threadIdx.x + 768 < NBLK_) s += part[threadIdx.x + 768];
    #pragma unroll
    for (int off = 32; off > 0; off >>= 1) s += __shfl_down(s, off, 64);
    __shared__ float ls[4];
    if ((threadIdx.x & 63) == 0) ls[threadIdx.x >> 6] = s;
    __syncthreads();
    if (threadIdx.x == 0)
        out[0] = ((ls[0] + ls[1]) + (ls[2] + ls[3])) * SCALE_;
}

}  // namespace

extern "C" void kernel_launch(void* const* d_in, const int* in_sizes, int n_in,
                              void* d_out, int out_size, void* d_ws, size_t ws_size,
                              hipStream_t stream) {
    const float* gt = (const float*)d_in[0];   // depth_gt (B,N,H,W)
    const float* dp = (const float*)d_in[1];   // depth (B,N*D,H,W)
    float* part = (float*)d_ws;                // 924 floats of scratch
    float* out  = (float*)d_out;
    depth_loss_part<<<NBLK_, 256, 0, stream>>>(gt, dp, part);
    depth_loss_final<<<1, 256, 0, stream>>>(part, out);
}